// Round 1
// 981.507 us; speedup vs baseline: 1.0138x; 1.0138x over previous
//
#include <hip/hip_runtime.h>
#include <hip/hip_bf16.h>
#include <math.h>

typedef unsigned short u16;
typedef unsigned int u32;
typedef short s8v __attribute__((ext_vector_type(8)));
typedef float f4v __attribute__((ext_vector_type(4)));

#define D_MODEL 1024
#define D_FF    4096
#define NE      24
#define T_TOT   2048
#define SLOTS   (2*T_TOT)
#define CAP     2112     // multiple of SBM=192, >= 2048 worst-case count rounded up
#define SBM     192      // m-supertile rows per block (3 x 64): 96 FLOP/B weight intensity
#define MT      3
#define BN      128
#define BK      32
#define MAXT    48       // sum ceil(c_e/192) <= (4096 + 24*191)/192 = 45

// ---- ws layout (bytes) ----
#define OFF_GATES   0                          // float [2048][2]
#define OFF_COUNTS  (OFF_GATES + T_TOT*2*4)    // int[24], padded
#define OFF_NT      (OFF_COUNTS + 128)         // int[1]
#define OFF_MT      (OFF_NT + 128)             // int[128]
#define OFF_TLIST   (OFF_MT + 512)             // int[24][CAP]
#define OFF_XB      (OFF_TLIST + NE*CAP*4)     // bf16 [2048][1024] (4 MB)
#define OFF_H       (OFF_XB + (size_t)T_TOT*D_MODEL*2)   // bf16 [SLOTS][D_FF]
#define OFF_Y       (OFF_H + (size_t)SLOTS*D_FF*2)       // float [SLOTS][D_MODEL]

typedef __attribute__((address_space(1))) unsigned int AS1_u32;
typedef __attribute__((address_space(3))) unsigned int AS3_u32;

// async 16B global->LDS (linear dest = wave base + lane*16)
__device__ __forceinline__ void gload16(const void* g, void* l) {
    __builtin_amdgcn_global_load_lds((const AS1_u32*)g, (AS3_u32*)l, 16, 0, 0);
}

// hardware RNE pack: 2 fp32 -> 2 bf16 in one u32 (lo = a, hi = b)
__device__ __forceinline__ u32 cvt_pk(float a, float b) {
    u32 r;
    asm("v_cvt_pk_bf16_f32 %0, %1, %2" : "=v"(r) : "v"(a), "v"(b));
    return r;
}

// ---------------- kernel 0: zero expert counts ----------------
__global__ void zero_kern(int* __restrict__ counts) {
    if (threadIdx.x < NE) counts[threadIdx.x] = 0;
}

// ---------------- kernel 0b: x fp32 -> bf16 (enables global_load_lds A-staging in GEMM1) ----
__global__ void xcvt_kern(const float* __restrict__ x, u16* __restrict__ xb) {
    int gid = blockIdx.x * 256 + threadIdx.x;      // 1024 blocks: 8 floats/thread
    const float4* xp = (const float4*)(x + (size_t)gid * 8);
    float4 a = xp[0], b = xp[1];
    uint4 o;
    o.x = cvt_pk(a.x, a.y);
    o.y = cvt_pk(a.z, a.w);
    o.z = cvt_pk(b.x, b.y);
    o.w = cvt_pk(b.z, b.w);
    ((uint4*)xb)[gid] = o;
}

// ---------------- kernel 1: gating (fp32 scores -> top2 -> softmax -> lists) ----------------
__global__ void gate_kern(const float* __restrict__ x, const float* __restrict__ gw,
                          const float* __restrict__ gb, float* __restrict__ gates,
                          int* __restrict__ counts, int* __restrict__ tlist) {
    int t = blockIdx.x;
    int lane = threadIdx.x;
    float acc[NE];
#pragma unroll
    for (int e = 0; e < NE; e++) acc[e] = 0.f;
    const float* xr = x + (size_t)t * D_MODEL;
#pragma unroll 4
    for (int i = 0; i < D_MODEL / 64; i++) {
        int d = lane + i * 64;
        float xv = xr[d];
        const float* g = gw + (size_t)d * NE;
#pragma unroll
        for (int e = 0; e < NE; e++) acc[e] = fmaf(xv, g[e], acc[e]);
    }
#pragma unroll
    for (int m = 1; m < 64; m <<= 1) {
#pragma unroll
        for (int e = 0; e < NE; e++) acc[e] += __shfl_xor(acc[e], m, 64);
    }
    if (lane == 0) {
        float v0 = -1e30f, v1 = -1e30f;
        int i0 = 0, i1 = 0;
#pragma unroll
        for (int e = 0; e < NE; e++) {
            float v = acc[e] + gb[e];
            if (v > v0) { v1 = v0; i1 = i0; v0 = v; i0 = e; }
            else if (v > v1) { v1 = v; i1 = e; }
        }
        float e1 = __expf(v1 - v0);
        float inv = 1.f / (1.f + e1);
        gates[t * 2 + 0] = inv;
        gates[t * 2 + 1] = e1 * inv;
        int p0 = atomicAdd(&counts[i0], 1);
        tlist[i0 * CAP + p0] = t * 2 + 0;
        int p1 = atomicAdd(&counts[i1], 1);
        tlist[i1 * CAP + p1] = t * 2 + 1;
    }
}

// ---------------- kernel 2: schedule (pad lists to 192, build supertile worklist) ----------------
__global__ void sched_kern(const int* __restrict__ counts, int* __restrict__ ntl,
                           int* __restrict__ mtl, int* __restrict__ tlist) {
    int tid = threadIdx.x;
    for (int idx = tid; idx < NE * SBM; idx += 256) {
        int e = idx / SBM, j = idx % SBM;
        int c = counts[e];
        int cr = ((c + SBM - 1) / SBM) * SBM;
        if (c + j < cr) tlist[e * CAP + c + j] = -1;
    }
    if (tid == 0) {
        int tot = 0;
        for (int e = 0; e < NE; e++) {
            int nt = (counts[e] + SBM - 1) / SBM;
            for (int i = 0; i < nt; i++) mtl[tot++] = (e << 16) | i;
        }
        ntl[0] = tot;
    }
}

// LDS layout (both GEMMs): rows of 32 bf16 (64 B), 16B chunks XOR-swizzled by (row>>2)&3.
//  - A staged by global_load_lds (linear dest); swizzle compensated on per-lane SOURCE addr.
//  - frag read phys chunk = quad ^ ((l16>>2)&3) -> 2-way bank aliasing (free).
//  - B transposed stores land 8-way (was 16-way with padded-stride layout).

// ---------------- kernel 3: grouped GEMM1  h = gelu(xb @ w1 + b1) ----------------
__global__ __launch_bounds__(256) void gemm1_kern(
    const u16* __restrict__ xb, const float* __restrict__ w1, const float* __restrict__ b1,
    const int* __restrict__ ntl, const int* __restrict__ mtl, const int* __restrict__ tlist,
    u16* __restrict__ h) {
    int mtile = blockIdx.y;
    if (mtile >= ntl[0]) return;
    int ent = mtl[mtile];
    int e = ent >> 16, tile = ent & 0xFFFF;
    int f0 = blockIdx.x * BN;
    const int* tl = tlist + e * CAP + tile * SBM;

    __shared__ u16 As[SBM * 32];   // 12 KB
    __shared__ u16 Bs[BN * 32];    // 8 KB

    int tid = threadIdx.x;
    int wave = tid >> 6, lane = tid & 63, quad = lane >> 4, l16 = lane & 15;

    // A-staging source ptrs: 3 chunks/thread, source pre-swizzled (inverse of read swizzle)
    const u16* asrc[3];
#pragma unroll
    for (int c = 0; c < 3; c++) {
        int i = c * 256 + tid;
        int row = i >> 2, pc = i & 3;
        int sl = tl[row]; if (sl < 0) sl = 0;          // clamp: garbage rows skipped in epilogue
        int lc = pc ^ ((row >> 2) & 3);
        asrc[c] = xb + (size_t)(sl >> 1) * D_MODEL + lc * 8;
    }

    // B staging: 4 n-cols x 4 k-rows per thread, reg transpose + hw cvt_pk
    int bn4 = (tid & 31) * 4, bkb = (tid >> 5) * 4;
    const float* bp = w1 + (size_t)e * D_MODEL * D_FF + f0 + bn4;
    int bwoff = bn4 * 32 + (((bkb >> 3) ^ (tid & 3)) << 3) + (bkb & 7);

    int pco = (quad ^ ((l16 >> 2) & 3)) << 3;   // frag read phys chunk offset (elems)

    f4v acc[MT][4][2];
#pragma unroll
    for (int m = 0; m < MT; m++)
#pragma unroll
        for (int i = 0; i < 4; i++)
#pragma unroll
            for (int j = 0; j < 2; j++) acc[m][i][j] = (f4v){0.f, 0.f, 0.f, 0.f};

    for (int k0 = 0; k0 < D_MODEL; k0 += BK) {
        float4 q0 = *(const float4*)(bp + (size_t)(k0 + bkb + 0) * D_FF);
        float4 q1 = *(const float4*)(bp + (size_t)(k0 + bkb + 1) * D_FF);
        float4 q2 = *(const float4*)(bp + (size_t)(k0 + bkb + 2) * D_FF);
        float4 q3 = *(const float4*)(bp + (size_t)(k0 + bkb + 3) * D_FF);
#pragma unroll
        for (int c = 0; c < 3; c++)
            gload16(asrc[c] + k0, &As[(c * 256 + tid) * 8]);
        const float* p0 = (const float*)&q0;
        const float* p1 = (const float*)&q1;
        const float* p2 = (const float*)&q2;
        const float* p3 = (const float*)&q3;
#pragma unroll
        for (int j = 0; j < 4; j++) {
            uint2 wv;
            wv.x = cvt_pk(p0[j], p1[j]);
            wv.y = cvt_pk(p2[j], p3[j]);
            *(uint2*)&Bs[bwoff + j * 32] = wv;
        }
        __syncthreads();

        s8v bfr[2];
#pragma unroll
        for (int nf = 0; nf < 2; nf++)
            bfr[nf] = *(const s8v*)&Bs[(wave * 32 + nf * 16 + l16) * 32 + pco];
#pragma unroll
        for (int m = 0; m < MT; m++) {
            s8v af[4];
#pragma unroll
            for (int mf = 0; mf < 4; mf++)
                af[mf] = *(const s8v*)&As[(m * 64 + mf * 16 + l16) * 32 + pco];
#pragma unroll
            for (int mf = 0; mf < 4; mf++)
#pragma unroll
                for (int nf = 0; nf < 2; nf++)
                    acc[m][mf][nf] = __builtin_amdgcn_mfma_f32_16x16x32_bf16(af[mf], bfr[nf], acc[m][mf][nf], 0, 0, 0);
        }
        __syncthreads();
    }

    // epilogue: bias + exact gelu -> bf16
    float bb[2];
#pragma unroll
    for (int nf = 0; nf < 2; nf++) bb[nf] = b1[e * D_FF + f0 + wave * 32 + nf * 16 + l16];
#pragma unroll
    for (int m = 0; m < MT; m++)
#pragma unroll
        for (int mf = 0; mf < 4; mf++) {
            int rowb = m * 64 + mf * 16 + quad * 4;
#pragma unroll
            for (int r = 0; r < 4; r++) {
                int slot = tl[rowb + r];
                if (slot < 0) continue;
                float v0 = acc[m][mf][0][r] + bb[0];
                float v1 = acc[m][mf][1][r] + bb[1];
                float g0 = 0.5f * v0 * (1.f + erff(v0 * 0.70710678118654752f));
                float g1 = 0.5f * v1 * (1.f + erff(v1 * 0.70710678118654752f));
                u32 pr = cvt_pk(g0, g1);
                u16* hp = h + (size_t)slot * D_FF + f0 + wave * 32 + l16;
                hp[0]  = (u16)pr;
                hp[16] = (u16)(pr >> 16);
            }
        }
}

// ---------------- kernel 4: grouped GEMM2  y = h @ w2 + b2 ----------------
__global__ __launch_bounds__(256) void gemm2_kern(
    const u16* __restrict__ h, const float* __restrict__ w2, const float* __restrict__ b2,
    const int* __restrict__ ntl, const int* __restrict__ mtl, const int* __restrict__ tlist,
    float* __restrict__ y) {
    int mtile = blockIdx.y;
    if (mtile >= ntl[0]) return;
    int ent = mtl[mtile];
    int e = ent >> 16, tile = ent & 0xFFFF;
    int d0 = blockIdx.x * BN;
    const int* tl = tlist + e * CAP + tile * SBM;

    __shared__ u16 As[SBM * 32];
    __shared__ u16 Bs[BN * 32];

    int tid = threadIdx.x;
    int wave = tid >> 6, lane = tid & 63, quad = lane >> 4, l16 = lane & 15;

    const u16* asrc[3];
#pragma unroll
    for (int c = 0; c < 3; c++) {
        int i = c * 256 + tid;
        int row = i >> 2, pc = i & 3;
        int sl = tl[row]; if (sl < 0) sl = 0;
        int lc = pc ^ ((row >> 2) & 3);
        asrc[c] = h + (size_t)sl * D_FF + lc * 8;
    }

    int bn4 = (tid & 31) * 4, bkb = (tid >> 5) * 4;
    const float* bp = w2 + (size_t)e * D_FF * D_MODEL + d0 + bn4;
    int bwoff = bn4 * 32 + (((bkb >> 3) ^ (tid & 3)) << 3) + (bkb & 7);

    int pco = (quad ^ ((l16 >> 2) & 3)) << 3;

    f4v acc[MT][4][2];
#pragma unroll
    for (int m = 0; m < MT; m++)
#pragma unroll
        for (int i = 0; i < 4; i++)
#pragma unroll
            for (int j = 0; j < 2; j++) acc[m][i][j] = (f4v){0.f, 0.f, 0.f, 0.f};

    for (int k0 = 0; k0 < D_FF; k0 += BK) {
        float4 q0 = *(const float4*)(bp + (size_t)(k0 + bkb + 0) * D_MODEL);
        float4 q1 = *(const float4*)(bp + (size_t)(k0 + bkb + 1) * D_MODEL);
        float4 q2 = *(const float4*)(bp + (size_t)(k0 + bkb + 2) * D_MODEL);
        float4 q3 = *(const float4*)(bp + (size_t)(k0 + bkb + 3) * D_MODEL);
#pragma unroll
        for (int c = 0; c < 3; c++)
            gload16(asrc[c] + k0, &As[(c * 256 + tid) * 8]);
        const float* p0 = (const float*)&q0;
        const float* p1 = (const float*)&q1;
        const float* p2 = (const float*)&q2;
        const float* p3 = (const float*)&q3;
#pragma unroll
        for (int j = 0; j < 4; j++) {
            uint2 wv;
            wv.x = cvt_pk(p0[j], p1[j]);
            wv.y = cvt_pk(p2[j], p3[j]);
            *(uint2*)&Bs[bwoff + j * 32] = wv;
        }
        __syncthreads();

        s8v bfr[2];
#pragma unroll
        for (int nf = 0; nf < 2; nf++)
            bfr[nf] = *(const s8v*)&Bs[(wave * 32 + nf * 16 + l16) * 32 + pco];
#pragma unroll
        for (int m = 0; m < MT; m++) {
            s8v af[4];
#pragma unroll
            for (int mf = 0; mf < 4; mf++)
                af[mf] = *(const s8v*)&As[(m * 64 + mf * 16 + l16) * 32 + pco];
#pragma unroll
            for (int mf = 0; mf < 4; mf++)
#pragma unroll
                for (int nf = 0; nf < 2; nf++)
                    acc[m][mf][nf] = __builtin_amdgcn_mfma_f32_16x16x32_bf16(af[mf], bfr[nf], acc[m][mf][nf], 0, 0, 0);
        }
        __syncthreads();
    }

    float bb[2];
#pragma unroll
    for (int nf = 0; nf < 2; nf++) bb[nf] = b2[e * D_MODEL + d0 + wave * 32 + nf * 16 + l16];
#pragma unroll
    for (int m = 0; m < MT; m++)
#pragma unroll
        for (int mf = 0; mf < 4; mf++) {
            int rowb = m * 64 + mf * 16 + quad * 4;
#pragma unroll
            for (int r = 0; r < 4; r++) {
                int slot = tl[rowb + r];
                if (slot < 0) continue;
                float* yp = y + (size_t)slot * D_MODEL + d0 + wave * 32 + l16;
                yp[0]  = acc[m][mf][0][r] + bb[0];
                yp[16] = acc[m][mf][1][r] + bb[1];
            }
        }
}

// ---------------- kernel 5: combine  out = x + g0*y[2t] + g1*y[2t+1] ----------------
__global__ void combine_kern(const float* __restrict__ x, const float* __restrict__ y,
                             const float* __restrict__ gates, float* __restrict__ out) {
    int gid = blockIdx.x * blockDim.x + threadIdx.x;
    int t = gid >> 7;
    int c = (gid & 127) << 3;
    float g0 = gates[t * 2 + 0], g1 = gates[t * 2 + 1];
    const float* xp = x + (size_t)t * D_MODEL + c;
    const float* ap = y + (size_t)(t * 2 + 0) * D_MODEL + c;
    const float* bp = y + (size_t)(t * 2 + 1) * D_MODEL + c;
    float* op = out + (size_t)t * D_MODEL + c;
    float4 x0 = *(const float4*)(xp), x1 = *(const float4*)(xp + 4);
    float4 a0 = *(const float4*)(ap), a1 = *(const float4*)(ap + 4);
    float4 b0 = *(const float4*)(bp), b1v = *(const float4*)(bp + 4);
    float4 o0, o1;
    o0.x = x0.x + g0 * a0.x + g1 * b0.x;
    o0.y = x0.y + g0 * a0.y + g1 * b0.y;
    o0.z = x0.z + g0 * a0.z + g1 * b0.z;
    o0.w = x0.w + g0 * a0.w + g1 * b0.w;
    o1.x = x1.x + g0 * a1.x + g1 * b1v.x;
    o1.y = x1.y + g0 * a1.y + g1 * b1v.y;
    o1.z = x1.z + g0 * a1.z + g1 * b1v.z;
    o1.w = x1.w + g0 * a1.w + g1 * b1v.w;
    *(float4*)(op) = o0;
    *(float4*)(op + 4) = o1;
}

extern "C" void kernel_launch(void* const* d_in, const int* in_sizes, int n_in,
                              void* d_out, int out_size, void* d_ws, size_t ws_size,
                              hipStream_t stream) {
    const float* x  = (const float*)d_in[0];
    const float* gw = (const float*)d_in[1];
    const float* gb = (const float*)d_in[2];
    const float* w1 = (const float*)d_in[3];
    const float* b1 = (const float*)d_in[4];
    const float* w2 = (const float*)d_in[5];
    const float* b2 = (const float*)d_in[6];
    float* out = (float*)d_out;

    char* ws = (char*)d_ws;
    float* gates = (float*)(ws + OFF_GATES);
    int* counts  = (int*)(ws + OFF_COUNTS);
    int* ntl     = (int*)(ws + OFF_NT);
    int* mtl     = (int*)(ws + OFF_MT);
    int* tlist   = (int*)(ws + OFF_TLIST);
    u16* xb      = (u16*)(ws + OFF_XB);
    u16* h       = (u16*)(ws + OFF_H);
    float* y     = (float*)(ws + OFF_Y);

    zero_kern<<<1, 64, 0, stream>>>(counts);
    xcvt_kern<<<T_TOT * D_MODEL / (8 * 256), 256, 0, stream>>>(x, xb);
    gate_kern<<<T_TOT, 64, 0, stream>>>(x, gw, gb, gates, counts, tlist);
    sched_kern<<<1, 256, 0, stream>>>(counts, ntl, mtl, tlist);
    gemm1_kern<<<dim3(D_FF / BN, MAXT), 256, 0, stream>>>(xb, w1, b1, ntl, mtl, tlist, h);
    gemm2_kern<<<dim3(D_MODEL / BN, MAXT), 256, 0, stream>>>(h, w2, b2, ntl, mtl, tlist, y);
    combine_kern<<<(T_TOT * D_MODEL / 8) / 256, 256, 0, stream>>>(x, y, gates, out);
}